// Round 1
// baseline (618.516 us; speedup 1.0000x reference)
//
#include <hip/hip_runtime.h>

#define NBINS (640 * 640)

// Scatter kernel: per point, write masked pc and atomic-max positive values
// into the per-bin accumulator (zero-initialized; output = max(seg, 0), so
// values <= 0 can never affect the result and are skipped entirely).
__global__ void pfe_scatter_kernel(const float4* __restrict__ pc,
                                   const float* __restrict__ lim,
                                   const int* __restrict__ size,
                                   float4* __restrict__ pc_masked,
                                   float* __restrict__ seg,
                                   int n) {
    // lim is row-major (2,2): [l00, l01, l10, l11]
    const float l00 = lim[0];
    const float l01 = lim[1];
    const float l10 = lim[2];
    const float l11 = lim[3];
    const int s0 = size[0];
    const int s1 = size[1];
    const float fs0 = (float)s0;
    const float fs1 = (float)s1;
    const float dx = l01 - l00;
    const float dy = l11 - l10;

    int i = blockIdx.x * blockDim.x + threadIdx.x;
    const int stride = gridDim.x * blockDim.x;
    for (; i < n; i += stride) {
        float4 p = pc[i];
        const bool mask = (p.x > l00) & (p.x < l01) & (p.y > l10) & (p.y < l11);

        float4 o = mask ? p : make_float4(0.f, 0.f, 0.f, 0.f);
        pc_masked[i] = o;

        if (mask) {
            // Replicate reference arithmetic exactly: IEEE f32 div, mul, trunc.
            int xi = (int)((p.x - l00) / dx * fs0);
            int yi = (int)((p.y - l10) / dy * fs1);
            long long idx = (long long)xi * (long long)s0 + (long long)yi;
            if (idx >= 0 && idx < (long long)NBINS) {
                float* b = seg + (size_t)idx * 4;
                // Non-negative IEEE floats order identically to their int
                // bit patterns; bins init to 0, and vals <= 0 are no-ops.
                if (p.x > 0.f) atomicMax((int*)&b[0], __float_as_int(p.x));
                if (p.y > 0.f) atomicMax((int*)&b[1], __float_as_int(p.y));
                if (p.z > 0.f) atomicMax((int*)&b[2], __float_as_int(p.z));
                if (p.w > 0.f) atomicMax((int*)&b[3], __float_as_int(p.w));
            }
        }
    }
}

extern "C" void kernel_launch(void* const* d_in, const int* in_sizes, int n_in,
                              void* d_out, int out_size, void* d_ws, size_t ws_size,
                              hipStream_t stream) {
    const float4* pc  = (const float4*)d_in[0];
    const float*  lim = (const float*)d_in[1];
    const int*    sz  = (const int*)d_in[2];

    const int n = in_sizes[0] / 4;             // 8,000,000 points
    float* out       = (float*)d_out;
    float* pc_masked = out;                    // n*4 floats
    float* seg       = out + (size_t)n * 4;    // NBINS*4 floats

    // Zero the segment-max region (output = max over positive vals, floor 0).
    hipMemsetAsync(seg, 0, (size_t)NBINS * 4 * sizeof(float), stream);

    const int block = 256;
    const int grid  = 2048;                    // grid-stride; ~15 pts/thread
    pfe_scatter_kernel<<<grid, block, 0, stream>>>(
        pc, lim, sz, (float4*)pc_masked, seg, n);
}

// Round 3
// 284.738 us; speedup vs baseline: 2.1722x; 2.1722x over previous
//
#include <hip/hip_runtime.h>

#define NBINS (640 * 640)

typedef float f4 __attribute__((ext_vector_type(4)));

__global__ __launch_bounds__(256) void pfe_scatter_kernel(
    const f4* __restrict__ pc,
    const float* __restrict__ lim,
    const int* __restrict__ size,
    f4* __restrict__ pc_masked,
    float* __restrict__ seg,
    int n) {
    // lim is row-major (2,2): [l00, l01, l10, l11]
    const float l00 = lim[0];
    const float l01 = lim[1];
    const float l10 = lim[2];
    const float l11 = lim[3];
    const int s0 = size[0];
    const int s1 = size[1];
    const float fs0 = (float)s0;
    const float fs1 = (float)s1;
    const float dx = l01 - l00;
    const float dy = l11 - l10;
    const f4 zero = {0.f, 0.f, 0.f, 0.f};

    const int stride = gridDim.x * blockDim.x;
    int i = blockIdx.x * blockDim.x + threadIdx.x;

    for (; i < n; i += 2 * stride) {
        const int ia = i;
        const int ib = i + stride;
        const bool hasB = ib < n;

        // Two independent point streams per iteration -> overlapped latency.
        f4 pa = __builtin_nontemporal_load(&pc[ia]);
        f4 pb;
        if (hasB) pb = __builtin_nontemporal_load(&pc[ib]);
        else      pb = (f4){l00, l10, 0.f, 0.f};  // fails mask

        const bool ma = (pa.x > l00) & (pa.x < l01) & (pa.y > l10) & (pa.y < l11);
        const bool mb = (pb.x > l00) & (pb.x < l01) & (pb.y > l10) & (pb.y < l11);

        __builtin_nontemporal_store(ma ? pa : zero, &pc_masked[ia]);
        if (hasB) __builtin_nontemporal_store(mb ? pb : zero, &pc_masked[ib]);

        // Bin indices (exact reference arithmetic: f32 div, mul, trunc-cast).
        int bina = -1, binb = -1;
        if (ma) {
            int xi = (int)((pa.x - l00) / dx * fs0);
            int yi = (int)((pa.y - l10) / dy * fs1);
            long long t = (long long)xi * (long long)s0 + (long long)yi;
            if (t >= 0 && t < (long long)NBINS) bina = (int)t;
        }
        if (mb) {
            int xi = (int)((pb.x - l00) / dx * fs0);
            int yi = (int)((pb.y - l10) / dy * fs1);
            long long t = (long long)xi * (long long)s0 + (long long)yi;
            if (t >= 0 && t < (long long)NBINS) binb = (int)t;
        }

        // Read-filter: bins only grow and start at 0, so a plain read sees a
        // value <= truth; skipping when p <= cur is always safe, and cur >= 0
        // subsumes the p > 0 positivity requirement.
        f4 cura, curb;
        if (bina >= 0) cura = *(const f4*)(seg + (size_t)bina * 4);
        if (binb >= 0) curb = *(const f4*)(seg + (size_t)binb * 4);

        if (bina >= 0) {
            float* b = seg + (size_t)bina * 4;
            if (pa.x > cura.x) atomicMax((int*)&b[0], __float_as_int(pa.x));
            if (pa.y > cura.y) atomicMax((int*)&b[1], __float_as_int(pa.y));
            if (pa.z > cura.z) atomicMax((int*)&b[2], __float_as_int(pa.z));
            if (pa.w > cura.w) atomicMax((int*)&b[3], __float_as_int(pa.w));
        }
        if (binb >= 0) {
            float* b = seg + (size_t)binb * 4;
            if (pb.x > curb.x) atomicMax((int*)&b[0], __float_as_int(pb.x));
            if (pb.y > curb.y) atomicMax((int*)&b[1], __float_as_int(pb.y));
            if (pb.z > curb.z) atomicMax((int*)&b[2], __float_as_int(pb.z));
            if (pb.w > curb.w) atomicMax((int*)&b[3], __float_as_int(pb.w));
        }
    }
}

extern "C" void kernel_launch(void* const* d_in, const int* in_sizes, int n_in,
                              void* d_out, int out_size, void* d_ws, size_t ws_size,
                              hipStream_t stream) {
    const f4*    pc  = (const f4*)d_in[0];
    const float* lim = (const float*)d_in[1];
    const int*   sz  = (const int*)d_in[2];

    const int n = in_sizes[0] / 4;             // 8,000,000 points
    float* out       = (float*)d_out;
    float* pc_masked = out;                    // n*4 floats
    float* seg       = out + (size_t)n * 4;    // NBINS*4 floats

    // Zero the segment-max region (output = max over positive vals, floor 0).
    (void)hipMemsetAsync(seg, 0, (size_t)NBINS * 4 * sizeof(float), stream);

    const int block = 256;
    const int grid  = 2048;                    // 524288 threads = max resident
    pfe_scatter_kernel<<<grid, block, 0, stream>>>(
        pc, lim, sz, (f4*)pc_masked, seg, n);
}

// Round 4
// 274.366 us; speedup vs baseline: 2.2543x; 1.0378x over previous
//
#include <hip/hip_runtime.h>

#define NBINS (640 * 640)

typedef float f4 __attribute__((ext_vector_type(4)));

__global__ __launch_bounds__(256) void pfe_scatter_kernel(
    const f4* __restrict__ pc,
    const float* __restrict__ lim,
    const int* __restrict__ size,
    f4* __restrict__ pc_masked,
    float* __restrict__ seg,
    int n) {
    // lim is row-major (2,2): [l00, l01, l10, l11]
    const float l00 = lim[0];
    const float l01 = lim[1];
    const float l10 = lim[2];
    const float l11 = lim[3];
    const int s0 = size[0];
    const float fs0 = (float)size[0];
    const float fs1 = (float)size[1];
    const float dx = l01 - l00;
    const float dy = l11 - l10;
    const f4 zero = {0.f, 0.f, 0.f, 0.f};

    const int stride = gridDim.x * blockDim.x;
    int base = blockIdx.x * blockDim.x + threadIdx.x;

    for (; base < n; base += 4 * stride) {
        // Phase 1: issue all 4 point loads (cached — L3 serves replays).
        f4 p[4];
        bool live[4];
        #pragma unroll
        for (int u = 0; u < 4; ++u) {
            const int i = base + u * stride;
            live[u] = i < n;
            p[u] = live[u] ? pc[i] : (f4){l00, l10, 0.f, 0.f};  // fails mask
        }

        // Phase 2: masks, bins, masked stores (nt: write-once stream).
        int bin[4];
        #pragma unroll
        for (int u = 0; u < 4; ++u) {
            const bool m = (p[u].x > l00) & (p[u].x < l01) &
                           (p[u].y > l10) & (p[u].y < l11);
            bin[u] = -1;
            if (m) {
                // Exact reference arithmetic: IEEE f32 div, mul, trunc-cast.
                // Mask guarantees xi,yi >= 0; max idx 640*640+640 fits i32;
                // `< NBINS` reproduces segment_max's OOB drop.
                int xi = (int)((p[u].x - l00) / dx * fs0);
                int yi = (int)((p[u].y - l10) / dy * fs1);
                int t = xi * s0 + yi;
                if (t < NBINS) bin[u] = t;
            }
            if (live[u])
                __builtin_nontemporal_store(m ? p[u] : zero,
                                            &pc_masked[base + u * stride]);
        }

        // Phase 3: issue all filter reads (4 outstanding).
        // Bins only grow from 0, so a plain read sees a value <= truth;
        // skipping when p <= cur is always safe, and cur >= 0 subsumes p > 0.
        f4 cur[4];
        #pragma unroll
        for (int u = 0; u < 4; ++u)
            if (bin[u] >= 0) cur[u] = *(const f4*)(seg + (size_t)bin[u] * 4);

        // Phase 4: atomics only where the candidate exceeds the snapshot.
        #pragma unroll
        for (int u = 0; u < 4; ++u) {
            if (bin[u] < 0) continue;
            float* b = seg + (size_t)bin[u] * 4;
            if (p[u].x > cur[u].x) atomicMax((int*)&b[0], __float_as_int(p[u].x));
            if (p[u].y > cur[u].y) atomicMax((int*)&b[1], __float_as_int(p[u].y));
            if (p[u].z > cur[u].z) atomicMax((int*)&b[2], __float_as_int(p[u].z));
            if (p[u].w > cur[u].w) atomicMax((int*)&b[3], __float_as_int(p[u].w));
        }
    }
}

extern "C" void kernel_launch(void* const* d_in, const int* in_sizes, int n_in,
                              void* d_out, int out_size, void* d_ws, size_t ws_size,
                              hipStream_t stream) {
    const f4*    pc  = (const f4*)d_in[0];
    const float* lim = (const float*)d_in[1];
    const int*   sz  = (const int*)d_in[2];

    const int n = in_sizes[0] / 4;             // 8,000,000 points
    float* out       = (float*)d_out;
    float* pc_masked = out;                    // n*4 floats
    float* seg       = out + (size_t)n * 4;    // NBINS*4 floats

    // Zero the segment-max region (output = max over positive vals, floor 0).
    (void)hipMemsetAsync(seg, 0, (size_t)NBINS * 4 * sizeof(float), stream);

    const int block = 256;
    const int grid  = 2048;                    // 524288 threads = max resident
    pfe_scatter_kernel<<<grid, block, 0, stream>>>(
        pc, lim, sz, (f4*)pc_masked, seg, n);
}

// Round 5
// 250.920 us; speedup vs baseline: 2.4650x; 1.0934x over previous
//
#include <hip/hip_runtime.h>

#define NBINS   (640 * 640)
#define GRID_X  640
#define REGIONS 256
#define P1_BLOCK 256
#define P1_PTS   4096                 // points per P1 block
#define P1_K     (P1_PTS / P1_BLOCK)  // 16
#define P2_BLOCK 1024

typedef float f4 __attribute__((ext_vector_type(4)));

// Exact reference arithmetic: IEEE f32 div/mul, trunc cast. Returns bin in
// [0, NBINS) or -1 (fails mask or segment_max OOB-drop).
__device__ __forceinline__ int point_bin(f4 p, float l00, float l01, float l10,
                                         float l11, float dx, float dy,
                                         float fs0, float fs1, int s0) {
    bool m = (p.x > l00) & (p.x < l01) & (p.y > l10) & (p.y < l11);
    if (!m) return -1;
    int xi = (int)((p.x - l00) / dx * fs0);
    int yi = (int)((p.y - l10) / dy * fs1);
    int t = xi * s0 + yi;            // mask => xi,yi >= 0; max fits i32
    return (t < NBINS) ? t : -1;
}

// region = (row * 410) >> 10  maps rows 0..639 onto 0..255 (2-3 rows each).
__device__ __forceinline__ int bin_region(int bin) {
    return (int)(((unsigned)(bin / GRID_X) * 410u) >> 10);
}

// ---------------- Pass 1: stream + bucket ----------------
__global__ __launch_bounds__(P1_BLOCK) void pfe_pass1(
    const f4* __restrict__ pc, const float* __restrict__ lim,
    const int* __restrict__ size, f4* __restrict__ pc_masked,
    float* __restrict__ seg, f4* __restrict__ bvals,
    unsigned* __restrict__ bbins, unsigned* __restrict__ cursors,
    int cap, int n) {
    __shared__ unsigned hist[REGIONS];
    __shared__ unsigned woff[REGIONS];   // global running slot cursor

    const float l00 = lim[0], l01 = lim[1], l10 = lim[2], l11 = lim[3];
    const int s0 = size[0];
    const float fs0 = (float)size[0], fs1 = (float)size[1];
    const float dx = l01 - l00, dy = l11 - l10;
    const f4 zero = {0.f, 0.f, 0.f, 0.f};

    for (int r = threadIdx.x; r < REGIONS; r += P1_BLOCK) hist[r] = 0;
    __syncthreads();

    const int base = blockIdx.x * P1_PTS;

    // Phase A: stream pc_masked, count per-region masked points.
    for (int k = 0; k < P1_K; ++k) {
        int i = base + k * P1_BLOCK + threadIdx.x;
        if (i < n) {
            f4 p = pc[i];
            int bin = point_bin(p, l00, l01, l10, l11, dx, dy, fs0, fs1, s0);
            __builtin_nontemporal_store(bin >= 0 ? p : zero, &pc_masked[i]);
            if (bin >= 0) atomicAdd(&hist[bin_region(bin)], 1u);
        }
    }
    __syncthreads();

    // Phase B: one global base alloc per non-empty region.
    for (int r = threadIdx.x; r < REGIONS; r += P1_BLOCK) {
        unsigned c = hist[r];
        unsigned g = 0;
        if (c) g = atomicAdd(&cursors[r], c);
        woff[r] = g;
    }
    __syncthreads();

    // Phase C: re-read points (L2/L3-hot), write to bucket slots.
    for (int k = 0; k < P1_K; ++k) {
        int i = base + k * P1_BLOCK + threadIdx.x;
        if (i < n) {
            f4 p = pc[i];
            int bin = point_bin(p, l00, l01, l10, l11, dx, dy, fs0, fs1, s0);
            if (bin >= 0) {
                int reg = bin_region(bin);
                unsigned s = atomicAdd(&woff[reg], 1u);  // global slot index
                if (s < (unsigned)cap) {
                    size_t slot = (size_t)reg * cap + s;
                    bbins[slot] = (unsigned)bin;
                    bvals[slot] = p;
                } else {
                    // Overflow fallback: filtered device atomics (rare/never).
                    float* b = seg + (size_t)bin * 4;
                    f4 cur = *(const f4*)b;
                    if (p.x > cur.x) atomicMax((int*)&b[0], __float_as_int(p.x));
                    if (p.y > cur.y) atomicMax((int*)&b[1], __float_as_int(p.y));
                    if (p.z > cur.z) atomicMax((int*)&b[2], __float_as_int(p.z));
                    if (p.w > cur.w) atomicMax((int*)&b[3], __float_as_int(p.w));
                }
            }
        }
    }
}

// ---------------- Pass 2: exclusive gather per region ----------------
__global__ __launch_bounds__(P2_BLOCK) void pfe_pass2(
    const f4* __restrict__ bvals, const unsigned* __restrict__ bbins,
    const unsigned* __restrict__ cursors, int cap, float* __restrict__ seg) {
    const int r = blockIdx.x;
    const int xlo = (r * 1024 + 409) / 410;
    int xhi = ((r + 1) * 1024 + 409) / 410 - 1;
    if (xhi > GRID_X - 1) xhi = GRID_X - 1;
    const int b0 = xlo * GRID_X;
    const int nb = (xhi - xlo + 1) * GRID_X;   // <= 3*640

    __shared__ int tile[3 * GRID_X * 4];       // fp32 bits, all >= 0
    for (int j = threadIdx.x; j < nb * 4; j += P2_BLOCK) tile[j] = 0;
    __syncthreads();

    unsigned cf = cursors[r];
    int cnt = (int)(cf < (unsigned)cap ? cf : (unsigned)cap);
    const size_t rb = (size_t)r * cap;
    for (int i = threadIdx.x; i < cnt; i += P2_BLOCK) {
        unsigned bin = bbins[rb + i];
        f4 v = bvals[rb + i];
        int t = ((int)bin - b0) * 4;
        // Non-negative floats order as their int bits; skip non-positives.
        if (v.x > 0.f) atomicMax(&tile[t + 0], __float_as_int(v.x));
        if (v.y > 0.f) atomicMax(&tile[t + 1], __float_as_int(v.y));
        if (v.z > 0.f) atomicMax(&tile[t + 2], __float_as_int(v.z));
        if (v.w > 0.f) atomicMax(&tile[t + 3], __float_as_int(v.w));
    }
    __syncthreads();

    // Merge with seg (holds only rare overflow-path maxes, else zeros).
    for (int j = threadIdx.x; j < nb; j += P2_BLOCK) {
        f4 s = *(const f4*)(seg + (size_t)(b0 + j) * 4);
        f4 o;
        o.x = fmaxf(__int_as_float(tile[j * 4 + 0]), s.x);
        o.y = fmaxf(__int_as_float(tile[j * 4 + 1]), s.y);
        o.z = fmaxf(__int_as_float(tile[j * 4 + 2]), s.z);
        o.w = fmaxf(__int_as_float(tile[j * 4 + 3]), s.w);
        *(f4*)(seg + (size_t)(b0 + j) * 4) = o;
    }
}

// ---------------- Fallback (round-4 kernel, proven) ----------------
__global__ __launch_bounds__(256) void pfe_scatter_kernel(
    const f4* __restrict__ pc, const float* __restrict__ lim,
    const int* __restrict__ size, f4* __restrict__ pc_masked,
    float* __restrict__ seg, int n) {
    const float l00 = lim[0], l01 = lim[1], l10 = lim[2], l11 = lim[3];
    const int s0 = size[0];
    const float fs0 = (float)size[0], fs1 = (float)size[1];
    const float dx = l01 - l00, dy = l11 - l10;
    const f4 zero = {0.f, 0.f, 0.f, 0.f};

    const int stride = gridDim.x * blockDim.x;
    int base = blockIdx.x * blockDim.x + threadIdx.x;
    for (; base < n; base += 4 * stride) {
        f4 p[4]; bool live[4]; int bin[4];
        #pragma unroll
        for (int u = 0; u < 4; ++u) {
            const int i = base + u * stride;
            live[u] = i < n;
            p[u] = live[u] ? pc[i] : (f4){l00, l10, 0.f, 0.f};
        }
        #pragma unroll
        for (int u = 0; u < 4; ++u) {
            bin[u] = point_bin(p[u], l00, l01, l10, l11, dx, dy, fs0, fs1, s0);
            if (live[u])
                __builtin_nontemporal_store(bin[u] >= 0 ? p[u] : zero,
                                            &pc_masked[base + u * stride]);
        }
        f4 cur[4];
        #pragma unroll
        for (int u = 0; u < 4; ++u)
            if (bin[u] >= 0) cur[u] = *(const f4*)(seg + (size_t)bin[u] * 4);
        #pragma unroll
        for (int u = 0; u < 4; ++u) {
            if (bin[u] < 0) continue;
            float* b = seg + (size_t)bin[u] * 4;
            if (p[u].x > cur[u].x) atomicMax((int*)&b[0], __float_as_int(p[u].x));
            if (p[u].y > cur[u].y) atomicMax((int*)&b[1], __float_as_int(p[u].y));
            if (p[u].z > cur[u].z) atomicMax((int*)&b[2], __float_as_int(p[u].z));
            if (p[u].w > cur[u].w) atomicMax((int*)&b[3], __float_as_int(p[u].w));
        }
    }
}

extern "C" void kernel_launch(void* const* d_in, const int* in_sizes, int n_in,
                              void* d_out, int out_size, void* d_ws, size_t ws_size,
                              hipStream_t stream) {
    const f4*    pc  = (const f4*)d_in[0];
    const float* lim = (const float*)d_in[1];
    const int*   sz  = (const int*)d_in[2];

    const int n = in_sizes[0] / 4;             // 8,000,000 points
    float* out       = (float*)d_out;
    float* pc_masked = out;                    // n*4 floats
    float* seg       = out + (size_t)n * 4;    // NBINS*4 floats

    (void)hipMemsetAsync(seg, 0, (size_t)NBINS * 4 * sizeof(float), stream);

    // Workspace budget: 20 B/slot * REGIONS * cap + cursors.
    const size_t fixed = REGIONS * sizeof(unsigned);
    int cap = 0;
    if (ws_size > fixed)
        cap = (int)((ws_size - fixed) / ((size_t)REGIONS * 20));
    if (cap > 32768) cap = 32768;

    if (cap >= 24576) {
        f4*       bvals   = (f4*)d_ws;
        unsigned* bbins   = (unsigned*)(bvals + (size_t)REGIONS * cap);
        unsigned* cursors = bbins + (size_t)REGIONS * cap;

        (void)hipMemsetAsync(cursors, 0, REGIONS * sizeof(unsigned), stream);

        const int p1_grid = (n + P1_PTS - 1) / P1_PTS;   // 1954
        pfe_pass1<<<p1_grid, P1_BLOCK, 0, stream>>>(
            pc, lim, sz, (f4*)pc_masked, seg, bvals, bbins, cursors, cap, n);
        pfe_pass2<<<REGIONS, P2_BLOCK, 0, stream>>>(
            bvals, bbins, cursors, cap, seg);
    } else {
        // Workspace too small: proven single-kernel path.
        pfe_scatter_kernel<<<2048, 256, 0, stream>>>(
            pc, lim, sz, (f4*)pc_masked, seg, n);
    }
}